// Round 16
// baseline (116.718 us; speedup 1.0000x reference)
//
#include <hip/hip_runtime.h>
#include <cmath>

// SSIM loss, vertical-first row-sliding kernel, merged 3D+2D dispatch.
// Round-16 = round-14 scaled to FOUR output rows per barrier interval:
// 16-slot register ring, insert 4 input rows/iter, 4 vpasses -> 4 LDS sets,
// ONE leading barrier, 4 INDEPENDENT hpass chains (4x MLP in the
// stall-dominated LDS-read section), trailing barrier. Barrier rate equals
// R14 (2 per 4 rows) but rendezvous skew amortizes over 2x the work.
// 3D re-banded to 32-row bands (steps/row 1.31 vs 1.45 -> ~10% less work).
// LDS 42 KB -> 3 blocks/CU (R14-proven); launch_bounds(256,3) relaxes the
// VGPR cap to ~170 so the 16-slot ring (64 VGPR) cannot spill (R15 lesson:
// cap 128 already nicked it). Prefetch in named registers only.

#define WSZ 11
#define IMG 512
#define SLICE (IMG * IMG)

typedef float f32x2 __attribute__((ext_vector_type(2)));
typedef float f32x4 __attribute__((ext_vector_type(4)));

struct G11 { float w[WSZ]; };

// LDS-visibility-only barrier: wait own LDS ops, rendezvous; vmem stays in flight.
__device__ __forceinline__ void row_barrier()
{
    asm volatile("s_waitcnt lgkmcnt(0)" ::: "memory");
    __builtin_amdgcn_s_barrier();
}

__global__ __launch_bounds__(256, 3)
void ssim_pk_kernel(const float* __restrict__ A3, const float* __restrict__ B3,
                    const float* __restrict__ A2, const float* __restrict__ B2,
                    double* __restrict__ acc, G11 gw)
{
    __shared__ f32x4 A4[4][262];   // (m1,m2) pairs, 3-slot pad each side
    __shared__ f32x4 B4[4][262];   // (xx,yy) pairs
    __shared__ f32x2 Z2[4][262];   // zz pairs
    __shared__ float bsum[4];

    const int tx = threadIdx.x;    // 0..255 = column pair index
    const int x0 = tx * 2;

    // decode work unit: [0,1024) = 3D slice-bands (64 slices x 16 bands of 32
    // rows), [1024,1280) = 2D bands (4 imgs x 64 bands of 8 rows, B2 = mean)
    const int unit = blockIdx.x;
    const float* Ap;
    const float* Bp;
    double* accp;
    int y0, BAND;
    if (unit < 1024) {
        int slice = unit >> 4;
        int band  = unit & 15;
        Ap = A3 + (long)slice * SLICE;
        Bp = B3 + (long)slice * SLICE;
        accp = acc + 0;
        y0 = band * 32;
        BAND = 32;
    } else {
        int uu = unit - 1024;
        int img  = uu >> 6;
        int band = uu & 63;
        Ap = A2 + (long)img * SLICE;
        Bp = B2 + (long)img * SLICE;
        accp = acc + 1;
        y0 = band * 8;
        BAND = 8;
    }
    const int ITER = BAND >> 2;    // 4 output rows per iteration (8 or 2)

    // zero pads: pair slots 0..2 and 259..261, all 4 sets (read-only after;
    // visible to all waves at the first leading barrier)
    if (tx < 3) {
        f32x4 z4 = {0.f, 0.f, 0.f, 0.f};
        f32x2 z2 = {0.f, 0.f};
        #pragma unroll
        for (int b = 0; b < 4; b++) {
            A4[b][tx] = z4; A4[b][259 + tx] = z4;
            B4[b][tx] = z4; B4[b][259 + tx] = z4;
            Z2[b][tx] = z2; Z2[b][259 + tx] = z2;
        }
    }

    // 16-slot register ring of raw (a,b) pairs; slot = t % 16, t = row-(y0-5)
    f32x2 ra[16], rb[16];

    float sum = 0.f;
    const f32x2 C1v = {1e-4f, 1e-4f};
    const f32x2 C2v = {9e-4f, 9e-4f};

    // warmup: insert input rows t = 0..9 (rows y0-5 .. y0+4)
    #pragma unroll
    for (int t = 0; t < 10; t++) {
        int r = y0 - 5 + t;
        f32x2 a = {0.f, 0.f}, b = {0.f, 0.f};
        if (r >= 0) {                       // r < IMG always holds in warmup
            a = *(const f32x2*)&Ap[(long)r * IMG + x0];
            b = *(const f32x2*)&Bp[(long)r * IMG + x0];
        }
        ra[t] = a; rb[t] = b;
    }
    #pragma unroll
    for (int t = 10; t < 16; t++) { ra[t] = (f32x2){0.f, 0.f}; rb[t] = (f32x2){0.f, 0.f}; }

    // prefetch iteration 0's four input rows (t = 10..13 -> rows y0+5..y0+8)
    f32x2 aN0 = {0.f, 0.f}, bN0 = aN0, aN1 = aN0, bN1 = aN0;
    f32x2 aN2 = aN0, bN2 = aN0, aN3 = aN0, bN3 = aN0;
    {
        int r = y0 + 5;
        if (r     < IMG) { aN0 = *(const f32x2*)&Ap[(long)(r    ) * IMG + x0];
                           bN0 = *(const f32x2*)&Bp[(long)(r    ) * IMG + x0]; }
        if (r + 1 < IMG) { aN1 = *(const f32x2*)&Ap[(long)(r + 1) * IMG + x0];
                           bN1 = *(const f32x2*)&Bp[(long)(r + 1) * IMG + x0]; }
        if (r + 2 < IMG) { aN2 = *(const f32x2*)&Ap[(long)(r + 2) * IMG + x0];
                           bN2 = *(const f32x2*)&Bp[(long)(r + 2) * IMG + x0]; }
        if (r + 3 < IMG) { aN3 = *(const f32x2*)&Ap[(long)(r + 3) * IMG + x0];
                           bN3 = *(const f32x2*)&Bp[(long)(r + 3) * IMG + x0]; }
    }

    // vertical 11-tap for one output row; reads slots (base+j)%16, writes set buf
    auto vpass = [&](int base, int buf) {
        f32x2 m1 = {0.f, 0.f}, m2 = m1, xx = m1, yy = m1, zz = m1;
        #pragma unroll
        for (int j = 0; j < 11; j++) {
            const int s = (base + j) % 16;           // compile-time
            const f32x2 g2 = {gw.w[j], gw.w[j]};
            f32x2 a = ra[s], b = rb[s];
            f32x2 ga = g2 * a, gb = g2 * b;
            m1 += ga; m2 += gb;
            xx += ga * a; yy += gb * b; zz += ga * b;
        }
        A4[buf][3 + tx] = __builtin_shufflevector(m1, m2, 0, 1, 2, 3);
        B4[buf][3 + tx] = __builtin_shufflevector(xx, yy, 0, 1, 2, 3);
        Z2[buf][3 + tx] = zz;
    };

    // horizontal 11-tap + SSIM for one buffered row
    auto hpass = [&](int buf) {
        f32x2 OM1 = {0.f, 0.f}, OM2 = OM1, OXX = OM1, OYY = OM1, OZZ = OM1;
        {   // jj = 0: only e1 with (g0, 0)
            f32x4 pa = A4[buf][tx], pb = B4[buf][tx];
            f32x2 pz = Z2[buf][tx];
            const f32x2 c = {gw.w[0], 0.f};
            OM1 += c * __builtin_shufflevector(pa, pa, 1, 1);
            OM2 += c * __builtin_shufflevector(pa, pa, 3, 3);
            OXX += c * __builtin_shufflevector(pb, pb, 1, 1);
            OYY += c * __builtin_shufflevector(pb, pb, 3, 3);
            OZZ += c * __builtin_shufflevector(pz, pz, 1, 1);
        }
        #pragma unroll
        for (int jj = 1; jj <= 5; jj++) {
            f32x4 pa = A4[buf][tx + jj], pb = B4[buf][tx + jj];
            f32x2 pz = Z2[buf][tx + jj];
            const f32x2 cA = {gw.w[2 * jj - 1], gw.w[2 * jj - 2]};
            const f32x2 cB = {gw.w[2 * jj],     gw.w[2 * jj - 1]};
            OM1 += cA * __builtin_shufflevector(pa, pa, 0, 0)
                 + cB * __builtin_shufflevector(pa, pa, 1, 1);
            OM2 += cA * __builtin_shufflevector(pa, pa, 2, 2)
                 + cB * __builtin_shufflevector(pa, pa, 3, 3);
            OXX += cA * __builtin_shufflevector(pb, pb, 0, 0)
                 + cB * __builtin_shufflevector(pb, pb, 1, 1);
            OYY += cA * __builtin_shufflevector(pb, pb, 2, 2)
                 + cB * __builtin_shufflevector(pb, pb, 3, 3);
            OZZ += cA * __builtin_shufflevector(pz, pz, 0, 0)
                 + cB * __builtin_shufflevector(pz, pz, 1, 1);
        }
        {   // jj = 6: only e0 with (0, g10)
            f32x4 pa = A4[buf][tx + 6], pb = B4[buf][tx + 6];
            f32x2 pz = Z2[buf][tx + 6];
            const f32x2 c = {0.f, gw.w[10]};
            OM1 += c * __builtin_shufflevector(pa, pa, 0, 0);
            OM2 += c * __builtin_shufflevector(pa, pa, 2, 2);
            OXX += c * __builtin_shufflevector(pb, pb, 0, 0);
            OYY += c * __builtin_shufflevector(pb, pb, 2, 2);
            OZZ += c * __builtin_shufflevector(pz, pz, 0, 0);
        }
        f32x2 m1s = OM1 * OM1, m2s = OM2 * OM2, m12 = OM1 * OM2;
        f32x2 s1 = OXX - m1s, s2 = OYY - m2s, s12 = OZZ - m12;
        f32x2 d1 = m1s + m2s + C1v;
        f32x2 d2 = s1 + s2 + C2v;
        f32x2 num = (2.f * m12 + C1v) * (2.f * s12 + C2v) * (s12 + C2v);
        float d3x = __builtin_amdgcn_sqrtf(s1.x) * __builtin_amdgcn_sqrtf(s2.x) + 9e-4f;
        float d3y = __builtin_amdgcn_sqrtf(s1.y) * __builtin_amdgcn_sqrtf(s2.y) + 9e-4f;
        sum += num.x * __builtin_amdgcn_rcpf(d1.x * d2.x * d3x);
        sum += num.y * __builtin_amdgcn_rcpf(d1.y * d2.y * d3y);
    };

    // main loop: iteration k emits output rows y0+4k .. y0+4k+3
    for (int kk = 0; kk < ITER; kk += 4) {
        #pragma unroll
        for (int u = 0; u < 4; u++) {
            const int k = kk + u;
            if (k < ITER) {                       // block-uniform
                // insert this iteration's four rows (t = 10+4k .. 13+4k);
                // 4*kk % 16 == 0, so slots depend only on u (static)
                const int s0 = (10 + 4 * u) % 16;
                const int s1 = (11 + 4 * u) % 16;
                const int s2 = (12 + 4 * u) % 16;
                const int s3 = (13 + 4 * u) % 16;
                ra[s0] = aN0; rb[s0] = bN0;
                ra[s1] = aN1; rb[s1] = bN1;
                ra[s2] = aN2; rb[s2] = bN2;
                ra[s3] = aN3; rb[s3] = bN3;

                // prefetch next iteration's four rows (in flight across barriers)
                {
                    int r = y0 + 9 + 4 * k;
                    aN0 = (f32x2){0.f, 0.f}; bN0 = aN0; aN1 = aN0; bN1 = aN0;
                    aN2 = aN0; bN2 = aN0; aN3 = aN0; bN3 = aN0;
                    if (k + 1 < ITER) {
                        if (r     < IMG) { aN0 = *(const f32x2*)&Ap[(long)(r    ) * IMG + x0];
                                           bN0 = *(const f32x2*)&Bp[(long)(r    ) * IMG + x0]; }
                        if (r + 1 < IMG) { aN1 = *(const f32x2*)&Ap[(long)(r + 1) * IMG + x0];
                                           bN1 = *(const f32x2*)&Bp[(long)(r + 1) * IMG + x0]; }
                        if (r + 2 < IMG) { aN2 = *(const f32x2*)&Ap[(long)(r + 2) * IMG + x0];
                                           bN2 = *(const f32x2*)&Bp[(long)(r + 2) * IMG + x0]; }
                        if (r + 3 < IMG) { aN3 = *(const f32x2*)&Ap[(long)(r + 3) * IMG + x0];
                                           bN3 = *(const f32x2*)&Bp[(long)(r + 3) * IMG + x0]; }
                    }
                }

                // 4 vertical sums -> 4 sets; 1 barrier; 4 independent h-passes;
                // trailing barrier protects sets from next iteration's writes
                vpass((4 * u + 0) % 16, 0);
                vpass((4 * u + 1) % 16, 1);
                vpass((4 * u + 2) % 16, 2);
                vpass((4 * u + 3) % 16, 3);
                row_barrier();
                hpass(0);
                hpass(1);
                hpass(2);
                hpass(3);
                row_barrier();
            }
        }
    }

    // block reduction: wave shuffle -> LDS -> one atomic per block
    for (int off = 32; off > 0; off >>= 1)
        sum += __shfl_down(sum, off, 64);
    if ((tx & 63) == 0) bsum[tx >> 6] = sum;
    __syncthreads();
    if (tx == 0) {
        float tot = bsum[0] + bsum[1] + bsum[2] + bsum[3];
        atomicAdd(accp, (double)tot);
    }
}

// b2 = mean over 16 depth slices of img2, vectorized float4 (BW-bound).
__global__ __launch_bounds__(256) void depth_mean4_kernel(
    const float4* __restrict__ img2, float4* __restrict__ b2)
{
    const int per = SLICE / 4;                       // 65536 float4 per slice
    int idx = blockIdx.x * 256 + threadIdx.x;        // 0 .. 4*per-1
    int b = idx >> 16;
    int p = idx & (per - 1);
    const float4* src = img2 + (long)b * 16 * per + p;
    float sx = 0.f, sy = 0.f, sz = 0.f, sw = 0.f;
    #pragma unroll
    for (int d = 0; d < 16; d++) {
        float4 v = src[(long)d * per];
        sx += v.x; sy += v.y; sz += v.z; sw += v.w;
    }
    float4 o; o.x = sx * 0.0625f; o.y = sy * 0.0625f; o.z = sz * 0.0625f; o.w = sw * 0.0625f;
    b2[idx] = o;
}

__global__ void finalize_kernel(const double* __restrict__ acc, float* __restrict__ out)
{
    double loss3 = 1.0 - acc[0] / (64.0 * (double)SLICE);
    double loss2 = 1.0 - acc[1] / (4.0 * (double)SLICE);
    out[0] = (float)(loss3 + loss2);
}

extern "C" void kernel_launch(void* const* d_in, const int* in_sizes, int n_in,
                              void* d_out, int out_size, void* d_ws, size_t ws_size,
                              hipStream_t stream)
{
    const float* img1_3d = (const float*)d_in[0];   // [4,1,16,512,512] -> 64 slices
    const float* img1_2d = (const float*)d_in[1];   // [4,1,512,512]
    const float* img2    = (const float*)d_in[2];   // [4,1,16,512,512]
    float* out = (float*)d_out;

    double* acc = (double*)d_ws;                    // [0]=3D sum, [1]=2D sum
    float*  b2  = (float*)((char*)d_ws + 256);      // 4 MB depth-mean buffer

    // Gaussian weights, like cv2.getGaussianKernel(11, 1.5) in double.
    G11 gw;
    {
        double g[WSZ], s = 0.0;
        for (int i = 0; i < WSZ; i++) {
            double xx = (double)i - (WSZ - 1) / 2.0;
            g[i] = std::exp(-(xx * xx) / (2.0 * 1.5 * 1.5));
            s += g[i];
        }
        for (int i = 0; i < WSZ; i++) gw.w[i] = (float)(g[i] / s);
    }

    hipMemsetAsync(acc, 0, 2 * sizeof(double), stream);

    // depth mean of img2 -> b2 (68 MB, ~12 us, proven)
    depth_mean4_kernel<<<(4 * SLICE / 4) / 256, 256, 0, stream>>>(
        (const float4*)img2, (float4*)b2);

    // merged SSIM: 1024 3D bands (64 slices x 16 bands of 32 rows)
    // + 256 2D bands (4 imgs x 64 bands of 8 rows) = 1280 blocks.
    ssim_pk_kernel<<<1280, 256, 0, stream>>>(img1_3d, img2, img1_2d, b2, acc, gw);

    finalize_kernel<<<1, 1, 0, stream>>>(acc, out);
}

// Round 17
// 95.277 us; speedup vs baseline: 1.2250x; 1.2250x over previous
//
#include <hip/hip_runtime.h>
#include <cmath>

// SSIM loss, vertical-first row-sliding kernel, merged 3D+2D dispatch.
// Round-17 = round-14's kernel byte-for-byte (proven best: 2 output rows per
// barrier interval, 12-slot ring, 4 LDS sets/42 KB, launch_bounds(256,4) ->
// VGPR 68 no spill) + round-16's orthogonal re-banding win: 3D bands of 32
// rows (halo overhead 1.31x vs 1.45x -> 12.5% fewer input-row loads; grid
// 1280 = 1024 3D + 256 2D). R16's 4-row interval itself spilled (VGPR 84 +
// 95 MB scratch) - ILP 2 is the register-budget sweet spot.

#define WSZ 11
#define IMG 512
#define SLICE (IMG * IMG)

typedef float f32x2 __attribute__((ext_vector_type(2)));
typedef float f32x4 __attribute__((ext_vector_type(4)));

struct G11 { float w[WSZ]; };

// LDS-visibility-only barrier: wait own LDS ops, rendezvous; vmem stays in flight.
__device__ __forceinline__ void row_barrier()
{
    asm volatile("s_waitcnt lgkmcnt(0)" ::: "memory");
    __builtin_amdgcn_s_barrier();
}

__global__ __launch_bounds__(256, 4)
void ssim_pk_kernel(const float* __restrict__ A3, const float* __restrict__ B3,
                    const float* __restrict__ A2, const float* __restrict__ B2,
                    double* __restrict__ acc, G11 gw)
{
    __shared__ f32x4 A4[4][262];   // (m1,m2) pairs, 3-slot pad each side
    __shared__ f32x4 B4[4][262];   // (xx,yy) pairs
    __shared__ f32x2 Z2[4][262];   // zz pairs
    __shared__ float bsum[4];

    const int tx = threadIdx.x;    // 0..255 = column pair index
    const int x0 = tx * 2;

    // decode work unit: [0,1024) = 3D slice-bands (64 slices x 16 bands of
    // 32 rows), [1024,1280) = 2D bands (4 imgs x 64 bands of 8 rows, B2=mean)
    const int unit = blockIdx.x;
    const float* Ap;
    const float* Bp;
    double* accp;
    int y0, BAND;
    if (unit < 1024) {
        int slice = unit >> 4;
        int band  = unit & 15;
        Ap = A3 + (long)slice * SLICE;
        Bp = B3 + (long)slice * SLICE;
        accp = acc + 0;
        y0 = band * 32;
        BAND = 32;
    } else {
        int uu = unit - 1024;
        int img  = uu >> 6;
        int band = uu & 63;
        Ap = A2 + (long)img * SLICE;
        Bp = B2 + (long)img * SLICE;
        accp = acc + 1;
        y0 = band * 8;
        BAND = 8;
    }
    const int ITER = BAND >> 1;    // 2 output rows per iteration (16 or 4)

    // zero pads: pair slots 0..2 and 259..261, all 4 buffer sets
    if (tx < 3) {
        f32x4 z4 = {0.f, 0.f, 0.f, 0.f};
        f32x2 z2 = {0.f, 0.f};
        #pragma unroll
        for (int b = 0; b < 4; b++) {
            A4[b][tx] = z4; A4[b][259 + tx] = z4;
            B4[b][tx] = z4; B4[b][259 + tx] = z4;
            Z2[b][tx] = z2; Z2[b][259 + tx] = z2;
        }
    }

    // 12-slot register ring of raw (a,b) pairs; slot = t % 12, t = row - (y0-5)
    f32x2 ra[12], rb[12];

    float sum = 0.f;
    const f32x2 C1v = {1e-4f, 1e-4f};
    const f32x2 C2v = {9e-4f, 9e-4f};

    // warmup: insert input rows t = 0..9 (rows y0-5 .. y0+4)
    #pragma unroll
    for (int t = 0; t < 10; t++) {
        int r = y0 - 5 + t;
        f32x2 a = {0.f, 0.f}, b = {0.f, 0.f};
        if (r >= 0) {                       // r < IMG always in warmup
            a = *(const f32x2*)&Ap[(long)r * IMG + x0];
            b = *(const f32x2*)&Bp[(long)r * IMG + x0];
        }
        ra[t] = a; rb[t] = b;
    }
    ra[10] = (f32x2){0.f, 0.f}; rb[10] = (f32x2){0.f, 0.f};
    ra[11] = (f32x2){0.f, 0.f}; rb[11] = (f32x2){0.f, 0.f};

    // prefetch iteration 0's two input rows (t = 10, 11 -> rows y0+5, y0+6)
    f32x2 aN0 = {0.f, 0.f}, bN0 = aN0, aN1 = aN0, bN1 = aN0;
    {
        int r0 = y0 + 5, r1 = y0 + 6;
        if (r0 < IMG) { aN0 = *(const f32x2*)&Ap[(long)r0 * IMG + x0];
                        bN0 = *(const f32x2*)&Bp[(long)r0 * IMG + x0]; }
        if (r1 < IMG) { aN1 = *(const f32x2*)&Ap[(long)r1 * IMG + x0];
                        bN1 = *(const f32x2*)&Bp[(long)r1 * IMG + x0]; }
    }

    // vertical 11-tap for one output row; slots (base+j)%12, weights g[j]
    auto vpass = [&](int base, int buf) {
        f32x2 m1 = {0.f, 0.f}, m2 = m1, xx = m1, yy = m1, zz = m1;
        #pragma unroll
        for (int j = 0; j < 11; j++) {
            const int s = (base + j) % 12;           // compile-time
            const f32x2 g2 = {gw.w[j], gw.w[j]};
            f32x2 a = ra[s], b = rb[s];
            f32x2 ga = g2 * a, gb = g2 * b;
            m1 += ga; m2 += gb;
            xx += ga * a; yy += gb * b; zz += ga * b;
        }
        A4[buf][3 + tx] = __builtin_shufflevector(m1, m2, 0, 1, 2, 3);
        B4[buf][3 + tx] = __builtin_shufflevector(xx, yy, 0, 1, 2, 3);
        Z2[buf][3 + tx] = zz;
    };

    // horizontal 11-tap + SSIM for one buffered row
    auto hpass = [&](int buf) {
        f32x2 OM1 = {0.f, 0.f}, OM2 = OM1, OXX = OM1, OYY = OM1, OZZ = OM1;
        {   // jj = 0: only e1 with (g0, 0)
            f32x4 pa = A4[buf][tx], pb = B4[buf][tx];
            f32x2 pz = Z2[buf][tx];
            const f32x2 c = {gw.w[0], 0.f};
            OM1 += c * __builtin_shufflevector(pa, pa, 1, 1);
            OM2 += c * __builtin_shufflevector(pa, pa, 3, 3);
            OXX += c * __builtin_shufflevector(pb, pb, 1, 1);
            OYY += c * __builtin_shufflevector(pb, pb, 3, 3);
            OZZ += c * __builtin_shufflevector(pz, pz, 1, 1);
        }
        #pragma unroll
        for (int jj = 1; jj <= 5; jj++) {
            f32x4 pa = A4[buf][tx + jj], pb = B4[buf][tx + jj];
            f32x2 pz = Z2[buf][tx + jj];
            const f32x2 cA = {gw.w[2 * jj - 1], gw.w[2 * jj - 2]};
            const f32x2 cB = {gw.w[2 * jj],     gw.w[2 * jj - 1]};
            OM1 += cA * __builtin_shufflevector(pa, pa, 0, 0)
                 + cB * __builtin_shufflevector(pa, pa, 1, 1);
            OM2 += cA * __builtin_shufflevector(pa, pa, 2, 2)
                 + cB * __builtin_shufflevector(pa, pa, 3, 3);
            OXX += cA * __builtin_shufflevector(pb, pb, 0, 0)
                 + cB * __builtin_shufflevector(pb, pb, 1, 1);
            OYY += cA * __builtin_shufflevector(pb, pb, 2, 2)
                 + cB * __builtin_shufflevector(pb, pb, 3, 3);
            OZZ += cA * __builtin_shufflevector(pz, pz, 0, 0)
                 + cB * __builtin_shufflevector(pz, pz, 1, 1);
        }
        {   // jj = 6: only e0 with (0, g10)
            f32x4 pa = A4[buf][tx + 6], pb = B4[buf][tx + 6];
            f32x2 pz = Z2[buf][tx + 6];
            const f32x2 c = {0.f, gw.w[10]};
            OM1 += c * __builtin_shufflevector(pa, pa, 0, 0);
            OM2 += c * __builtin_shufflevector(pa, pa, 2, 2);
            OXX += c * __builtin_shufflevector(pb, pb, 0, 0);
            OYY += c * __builtin_shufflevector(pb, pb, 2, 2);
            OZZ += c * __builtin_shufflevector(pz, pz, 0, 0);
        }
        f32x2 m1s = OM1 * OM1, m2s = OM2 * OM2, m12 = OM1 * OM2;
        f32x2 s1 = OXX - m1s, s2 = OYY - m2s, s12 = OZZ - m12;
        f32x2 d1 = m1s + m2s + C1v;
        f32x2 d2 = s1 + s2 + C2v;
        f32x2 num = (2.f * m12 + C1v) * (2.f * s12 + C2v) * (s12 + C2v);
        float d3x = __builtin_amdgcn_sqrtf(s1.x) * __builtin_amdgcn_sqrtf(s2.x) + 9e-4f;
        float d3y = __builtin_amdgcn_sqrtf(s1.y) * __builtin_amdgcn_sqrtf(s2.y) + 9e-4f;
        sum += num.x * __builtin_amdgcn_rcpf(d1.x * d2.x * d3x);
        sum += num.y * __builtin_amdgcn_rcpf(d1.y * d2.y * d3y);
    };

    // main loop: iteration k emits output rows y0+2k, y0+2k+1
    for (int kk = 0; kk < ITER; kk += 6) {
        #pragma unroll
        for (int u = 0; u < 6; u++) {
            const int k = kk + u;
            if (k < ITER) {                       // block-uniform
                // insert this iteration's two rows (t = 10+2k, 11+2k)
                const int s0 = (10 + 2 * u) % 12; // kk%6==0 -> static
                const int s1 = (11 + 2 * u) % 12;
                ra[s0] = aN0; rb[s0] = bN0;
                ra[s1] = aN1; rb[s1] = bN1;

                // prefetch next iteration's two rows (stay in flight across barrier)
                {
                    int r0 = y0 + 7 + 2 * k, r1 = r0 + 1;
                    aN0 = (f32x2){0.f, 0.f}; bN0 = aN0; aN1 = aN0; bN1 = aN0;
                    if (k + 1 < ITER) {
                        if (r0 < IMG) { aN0 = *(const f32x2*)&Ap[(long)r0 * IMG + x0];
                                        bN0 = *(const f32x2*)&Bp[(long)r0 * IMG + x0]; }
                        if (r1 < IMG) { aN1 = *(const f32x2*)&Ap[(long)r1 * IMG + x0];
                                        bN1 = *(const f32x2*)&Bp[(long)r1 * IMG + x0]; }
                    }
                }

                // two vertical sums -> two buffers; one barrier; two h-passes
                const int b0 = (u & 1) * 2;       // even k -> {0,1}, odd -> {2,3}
                vpass(2 * u,     b0);             // row o   uses slots (2k+j)%12
                vpass(2 * u + 1, b0 + 1);         // row o+1 uses slots (2k+1+j)%12
                row_barrier();
                hpass(b0);
                hpass(b0 + 1);
            }
        }
    }

    // block reduction: wave shuffle -> LDS -> one atomic per block
    for (int off = 32; off > 0; off >>= 1)
        sum += __shfl_down(sum, off, 64);
    if ((tx & 63) == 0) bsum[tx >> 6] = sum;
    __syncthreads();
    if (tx == 0) {
        float tot = bsum[0] + bsum[1] + bsum[2] + bsum[3];
        atomicAdd(accp, (double)tot);
    }
}

// b2 = mean over 16 depth slices of img2, vectorized float4 (BW-bound).
__global__ __launch_bounds__(256) void depth_mean4_kernel(
    const float4* __restrict__ img2, float4* __restrict__ b2)
{
    const int per = SLICE / 4;                       // 65536 float4 per slice
    int idx = blockIdx.x * 256 + threadIdx.x;        // 0 .. 4*per-1
    int b = idx >> 16;
    int p = idx & (per - 1);
    const float4* src = img2 + (long)b * 16 * per + p;
    float sx = 0.f, sy = 0.f, sz = 0.f, sw = 0.f;
    #pragma unroll
    for (int d = 0; d < 16; d++) {
        float4 v = src[(long)d * per];
        sx += v.x; sy += v.y; sz += v.z; sw += v.w;
    }
    float4 o; o.x = sx * 0.0625f; o.y = sy * 0.0625f; o.z = sz * 0.0625f; o.w = sw * 0.0625f;
    b2[idx] = o;
}

__global__ void finalize_kernel(const double* __restrict__ acc, float* __restrict__ out)
{
    double loss3 = 1.0 - acc[0] / (64.0 * (double)SLICE);
    double loss2 = 1.0 - acc[1] / (4.0 * (double)SLICE);
    out[0] = (float)(loss3 + loss2);
}

extern "C" void kernel_launch(void* const* d_in, const int* in_sizes, int n_in,
                              void* d_out, int out_size, void* d_ws, size_t ws_size,
                              hipStream_t stream)
{
    const float* img1_3d = (const float*)d_in[0];   // [4,1,16,512,512] -> 64 slices
    const float* img1_2d = (const float*)d_in[1];   // [4,1,512,512]
    const float* img2    = (const float*)d_in[2];   // [4,1,16,512,512]
    float* out = (float*)d_out;

    double* acc = (double*)d_ws;                    // [0]=3D sum, [1]=2D sum
    float*  b2  = (float*)((char*)d_ws + 256);      // 4 MB depth-mean buffer

    // Gaussian weights, like cv2.getGaussianKernel(11, 1.5) in double.
    G11 gw;
    {
        double g[WSZ], s = 0.0;
        for (int i = 0; i < WSZ; i++) {
            double xx = (double)i - (WSZ - 1) / 2.0;
            g[i] = std::exp(-(xx * xx) / (2.0 * 1.5 * 1.5));
            s += g[i];
        }
        for (int i = 0; i < WSZ; i++) gw.w[i] = (float)(g[i] / s);
    }

    hipMemsetAsync(acc, 0, 2 * sizeof(double), stream);

    // depth mean of img2 -> b2 (68 MB, ~12 us, proven)
    depth_mean4_kernel<<<(4 * SLICE / 4) / 256, 256, 0, stream>>>(
        (const float4*)img2, (float4*)b2);

    // merged SSIM: 1024 3D bands (64 slices x 16 bands of 32 rows)
    // + 256 2D bands (4 imgs x 64 bands of 8 rows) = 1280 blocks.
    ssim_pk_kernel<<<1280, 256, 0, stream>>>(img1_3d, img2, img1_2d, b2, acc, gw);

    finalize_kernel<<<1, 1, 0, stream>>>(acc, out);
}